// Round 6
// baseline (633.963 us; speedup 1.0000x reference)
//
#include <hip/hip_runtime.h>
#include <hip/hip_bf16.h>

// RWKV6 single-token self-attention, H=4096, NH=64, HS=64, TM=64, TD=128.
// R11: 4-dispatch chain. R10's sync-free fusions WITHOUT the ticket-spin
// (R10's only untested ingredient; suspected container-killer, same class
// as R3's grid.sync). Stream boundaries are the only cross-block sync.
//  kS : 80 blocks, one per (f, 256-wide h-slice): per-block LN recompute ->
//       full z[f] slice (w1 column-slab, L2-shared) -> mvals. Writes xl
//       (output 1) + dtype flag. No cross-block reduce anywhere.
//  kC : 1028 blocks: 0-3 self-contained decay chain (mw->dz->td, hidden
//       under the weight stream), 4-1027 matvecs r,k,v,g (R7 register
//       pipeline, 4 rows/wave), silu on g.
//  kD : 64 blocks: per-head state update (output 2), instance-norm,
//       gate -> og  (R9 proven body).
//  kE : 512 blocks: out0 = x + og @ Wo.T (output 0).

#define HDIM 4096
#define KC_BLOCKS 1028

// ws layout (floats)
#define WS_MV    0        // 5*4096: f=0 mw, 1 mk, 2 mv, 3 mr, 4 mg (kS->kC)
#define WS_TD    20480    // 4096  (kC decay -> kD)
#define WS_R     24576    // 4*4096 r,k,v,g (kC matvec -> kD)
#define WS_OG    40960    // 4096  (kD -> kE)
#define WS_FLAG  45056    // dtype flag
// total 45057 floats ~= 176 KB of d_ws

typedef unsigned short bfraw;

__device__ __forceinline__ float bf2f(bfraw u) {
    union { unsigned int u; float f; } v; v.u = ((unsigned int)u) << 16; return v.f;
}
__device__ __forceinline__ bfraw f2bf(float f) {
    union { float f; unsigned int u; } v; v.f = f;
    unsigned int u = v.u;
    unsigned int r = (u + 0x7fffu + ((u >> 16) & 1u)) >> 16;  // RNE
    return (bfraw)r;
}
__device__ __forceinline__ float ldin(const void* p, long long i, bool isbf) {
    return isbf ? bf2f(((const bfraw*)p)[i]) : ((const float*)p)[i];
}
__device__ __forceinline__ void stout(void* p, long long i, float v, bool isbf) {
    if (isbf) ((bfraw*)p)[i] = f2bf(v); else ((float*)p)[i] = v;
}
__device__ __forceinline__ float waveReduce(float v) {
    for (int m = 32; m; m >>= 1) v += __shfl_xor(v, m);
    return v;
}

// issue 8x16B weight loads for one bf16 row (8KB, coalesced)
__device__ __forceinline__ void issue8(const bfraw* __restrict__ wr, int lane,
                                       uint4 buf[8]) {
    #pragma unroll
    for (int it = 0; it < 8; ++it)
        buf[it] = *(const uint4*)(wr + it * 512 + lane * 8);
}
__device__ __forceinline__ float consume8(const uint4 buf[8],
                                          const float* __restrict__ mLds, int lane) {
    float acc = 0.f;
    #pragma unroll
    for (int it = 0; it < 8; ++it) {
        int base = it * 512 + lane * 8;
        float4 m0 = *(const float4*)(mLds + base);
        float4 m1 = *(const float4*)(mLds + base + 4);
        uint4 w4 = buf[it];
        acc += bf2f((bfraw)(w4.x & 0xffff)) * m0.x + bf2f((bfraw)(w4.x >> 16)) * m0.y;
        acc += bf2f((bfraw)(w4.y & 0xffff)) * m0.z + bf2f((bfraw)(w4.y >> 16)) * m0.w;
        acc += bf2f((bfraw)(w4.z & 0xffff)) * m1.x + bf2f((bfraw)(w4.z >> 16)) * m1.y;
        acc += bf2f((bfraw)(w4.w & 0xffff)) * m1.z + bf2f((bfraw)(w4.w >> 16)) * m1.w;
    }
    return acc;
}
__device__ __forceinline__ float dot_row_f32(const float* __restrict__ wr,
                                             const float* __restrict__ mLds, int lane) {
    float acc = 0.f;
    #pragma unroll
    for (int h = 0; h < 2; ++h) {
        float4 av[8];
        #pragma unroll
        for (int it = 0; it < 8; ++it)
            av[it] = *(const float4*)(wr + h * 2048 + it * 256 + lane * 4);
        #pragma unroll
        for (int it = 0; it < 8; ++it) {
            int base = h * 2048 + it * 256 + lane * 4;
            float4 m0 = *(const float4*)(mLds + base);
            float4 a = av[it];
            acc += a.x * m0.x + a.y * m0.y + a.z * m0.z + a.w * m0.w;
        }
    }
    return acc;
}

// ---------------- kS: LN + full maa LoRA chain, 80 independent blocks ----
// Block u: f = u>>4 (mix index), hs = u&15 (256-wide h-slice).
// Each block recomputes LN (inputs ~56KB, L2-hot) and its FULL z[f]
// (w1 column-slab 512KB, shared via L2 by the 16 blocks of the same f),
// so no cross-block reduction exists anywhere.
__global__ __launch_bounds__(256)
void kS_fused(const void* __restrict__ x, const void* __restrict__ st1,
              const void* __restrict__ lnw, const void* __restrict__ lnb,
              const void* __restrict__ tmx, const void* __restrict__ tm,
              const void* __restrict__ w1, const void* __restrict__ w2,
              void* __restrict__ dout, float* __restrict__ ws) {
    int tid = threadIdx.x, u = blockIdx.x;
    int f = u >> 4, hs = u & 15;
    int wid = tid >> 6, lane = tid & 63;
    bool isbf;
    {
        bfraw uu = ((const bfraw*)x)[lane];
        int e = (uu >> 7) & 0xFF;
        unsigned long long ball = __ballot(e >= 96 && e <= 144);
        isbf = __popcll(ball) >= 56;     // bf16 N(0,1): ~64/64 sane exponents
    }
    if (u == 0 && tid == 0) ws[WS_FLAG] = isbf ? 1.0f : 0.0f;

    __shared__ float red[8];
    __shared__ __align__(16) float xxxL[HDIM];
    __shared__ float zpart[4][64];
    __shared__ float zlL[64];
    // LN stats over full x
    float xv[16]; float s1 = 0.f, s2 = 0.f;
    for (int k = 0; k < 16; ++k) {
        float v = ldin(x, tid + k * 256, isbf);
        xv[k] = v; s1 += v; s2 += v * v;
    }
    s1 = waveReduce(s1); s2 = waveReduce(s2);
    if (lane == 0) { red[wid] = s1; red[4 + wid] = s2; }
    __syncthreads();
    float t1 = red[0] + red[1] + red[2] + red[3];
    float t2 = red[4] + red[5] + red[6] + red[7];
    float mu = t1 * (1.0f / HDIM);
    float var = fmaxf(t2 * (1.0f / HDIM) - mu * mu, 0.0f);
    float rstd = rsqrtf(var + 1e-5f);
    float xl_m = 0.f, sx_m = 0.f;        // xl/sx at this block's h = hs*256+tid
    for (int k = 0; k < 16; ++k) {
        int i = tid + k * 256;
        float xl = (xv[k] - mu) * rstd * ldin(lnw, i, isbf) + ldin(lnb, i, isbf);
        float sx = ldin(st1, i, isbf) - xl;
        xxxL[i] = xl + sx * ldin(tmx, i, isbf);
        if (k == hs) {
            xl_m = xl; sx_m = sx;
            if (f == 0) stout(dout, 4096 + i, xl, isbf);   // output 1: xl
        }
    }
    __syncthreads();
    // z[f][t] = xxx . w1[:, f*64+t]; wave wid covers j-quarter wid
    {
        int t = lane;
        float acc = 0.f;
        long long coff = (long long)f * 64 + t;
        int j0 = wid * 1024;
        #pragma unroll 8
        for (int j = j0; j < j0 + 1024; ++j)
            acc += xxxL[j] * ldin(w1, (long long)j * 320 + coff, isbf);
        zpart[wid][t] = acc;
    }
    __syncthreads();
    if (tid < 64)
        zlL[tid] = tanhf(zpart[0][tid] + zpart[1][tid] + zpart[2][tid] + zpart[3][tid]);
    __syncthreads();
    // mval[h] = xl + sx*(z . w2[f][:,h] + time_maa[f][h])
    int h = (hs << 8) + tid;
    float acc = 0.f;
    long long base = (long long)f * 64 * HDIM + h;
    #pragma unroll 8
    for (int t = 0; t < 64; ++t)
        acc += zlL[t] * ldin(w2, base + (long long)t * HDIM, isbf);
    ws[WS_MV + f * HDIM + h] = xl_m + sx_m * (acc + ldin(tm, (long long)f * HDIM + h, isbf));
}

// ---------------- kC: decay(0-3) || matvecs(4-1027) ----------------------
__global__ __launch_bounds__(256)
void kC_big(const void* __restrict__ dw1, const void* __restrict__ dw2,
            const void* __restrict__ tdec,
            const void* __restrict__ Wr, const void* __restrict__ Wk,
            const void* __restrict__ Wv, const void* __restrict__ Wg,
            float* __restrict__ ws) {
    bool isbf = ws[WS_FLAG] != 0.0f;
    int tid = threadIdx.x, bid = blockIdx.x;
    int wid = tid >> 6, lane = tid & 63;
    __shared__ __align__(16) float lm[HDIM];
    __shared__ float zr2[2][128];
    __shared__ float dzS[128];

    if (bid < 4) {
        // ---- decay chain (self-contained), hidden under weight stream ---
        for (int i = tid * 4; i < HDIM; i += 1024)
            *(float4*)(lm + i) = *(const float4*)(ws + WS_MV + i);   // mw
        __syncthreads();
        {   // dz[t] = tanh(mw . dw1[:,t]); half-sums per tid>>7
            int t = tid & 127, hf = tid >> 7;
            float acc = 0.f;
            int j0 = hf * 2048;
            #pragma unroll 8
            for (int j = j0; j < j0 + 2048; ++j)
                acc += lm[j] * ldin(dw1, (long long)j * 128 + t, isbf);
            zr2[hf][t] = acc;
        }
        __syncthreads();
        if (tid < 128) dzS[tid] = tanhf(zr2[0][tid] + zr2[1][tid]);
        __syncthreads();
        // td slice: 1024 outputs per block
        for (int k = 0; k < 4; ++k) {
            int i = bid * 1024 + k * 256 + tid;
            float a = 0.f;
            #pragma unroll 8
            for (int t = 0; t < 128; ++t)
                a += dzS[t] * ldin(dw2, (long long)t * HDIM + i, isbf);
            float tv = a + ldin(tdec, i, isbf);
            tv = fminf(fmaxf(tv, -9.72f), 2.27f);
            ws[WS_TD + i] = expf(-expf(tv));
        }
        return;
    }
    // ---- matvec (R7 register pipeline, 4 rows/wave) ---------------------
    int k4b = bid - 4;
    int mat = k4b >> 8, bb = k4b & 255;
    const void* W; const float* msrc;
    if (mat == 0)      { W = Wr; msrc = ws + WS_MV + 3 * HDIM; }
    else if (mat == 1) { W = Wk; msrc = ws + WS_MV + 1 * HDIM; }
    else if (mat == 2) { W = Wv; msrc = ws + WS_MV + 2 * HDIM; }
    else               { W = Wg; msrc = ws + WS_MV + 4 * HDIM; }
    float* y = ws + WS_R + mat * HDIM;
    for (int i = tid * 4; i < HDIM; i += 1024)
        *(float4*)(lm + i) = *(const float4*)(msrc + i);
    __syncthreads();
    int r0 = bb * 16 + wid * 4;
    float acc0, acc1, acc2, acc3;
    if (isbf) {
        const bfraw* w0 = (const bfraw*)W + (long long)r0 * HDIM;
        uint4 A[8], B[8];
        issue8(w0, lane, A);
        issue8(w0 + HDIM, lane, B);
        __builtin_amdgcn_sched_barrier(0);
        acc0 = consume8(A, lm, lane);
        issue8(w0 + 2 * HDIM, lane, A);
        __builtin_amdgcn_sched_barrier(0);
        acc1 = consume8(B, lm, lane);
        issue8(w0 + 3 * HDIM, lane, B);
        __builtin_amdgcn_sched_barrier(0);
        acc2 = consume8(A, lm, lane);
        acc3 = consume8(B, lm, lane);
    } else {
        const float* w0 = (const float*)W + (long long)r0 * HDIM;
        acc0 = dot_row_f32(w0, lm, lane);
        acc1 = dot_row_f32(w0 + HDIM, lm, lane);
        acc2 = dot_row_f32(w0 + 2 * HDIM, lm, lane);
        acc3 = dot_row_f32(w0 + 3 * HDIM, lm, lane);
    }
    acc0 = waveReduce(acc0); acc1 = waveReduce(acc1);
    acc2 = waveReduce(acc2); acc3 = waveReduce(acc3);
    if (lane == 0) {
        if (mat == 3) {
            acc0 = acc0 / (1.0f + expf(-acc0));
            acc1 = acc1 / (1.0f + expf(-acc1));
            acc2 = acc2 / (1.0f + expf(-acc2));
            acc3 = acc3 / (1.0f + expf(-acc3));
        }
        y[r0] = acc0; y[r0 + 1] = acc1; y[r0 + 2] = acc2; y[r0 + 3] = acc3;
    }
}

// ---------------- kD: per-head state update + readout + IN + gate --------
__global__ __launch_bounds__(64)
void kD_heads(const void* __restrict__ state2, const void* __restrict__ tfirst,
              const void* __restrict__ lnxw, const void* __restrict__ lnxb,
              void* __restrict__ dout, float* __restrict__ ws) {
    bool isbf = ws[WS_FLAG] != 0.0f;
    int h = blockIdx.x, j = threadIdx.x;
    int gi = h * 64 + j;
    float rj = ws[WS_R + gi], kj = ws[WS_R + HDIM + gi];
    float vj = ws[WS_R + 2 * HDIM + gi], gj = ws[WS_R + 3 * HDIM + gi];
    float tdj = ws[WS_TD + gi];
    float tfj = ldin(tfirst, gi, isbf);
    __shared__ float lr[64], lk[64], ltd[64];
    lr[j] = rj; lk[j] = kj; ltd[j] = tdj;
    float c = waveReduce(rj * kj * tfj);   // sum_i r_i k_i tf_i
    __syncthreads();
    float acc = 0.f;
    long long sbase = (long long)h * 4096 + j;
    #pragma unroll 8
    for (int i = 0; i < 64; ++i) {
        float s = ldin(state2, sbase + i * 64, isbf);
        acc += lr[i] * s;                                            // r @ state2 part
        stout(dout, 8192 + sbase + i * 64, lk[i] * vj + s * ltd[i], isbf);  // output 2
    }
    float oh = vj * c + acc;                            // r @ (kv*tf + s)
    float s1 = waveReduce(oh);
    float s2 = waveReduce(oh * oh);
    float mu = s1 * (1.0f / 64.0f);
    float var = fmaxf(s2 * (1.0f / 64.0f) - mu * mu, 0.0f);
    float rstd = rsqrtf(var + 1e-5f);
    float o = (oh - mu) * rstd * ldin(lnxw, gi, isbf) + ldin(lnxb, gi, isbf);
    ws[WS_OG + gi] = o * gj;
}

// ---------------- kE: out0 = x + og @ Wo.T -------------------------------
__global__ __launch_bounds__(256)
void kE_out(const void* __restrict__ Wo, const void* __restrict__ x,
            void* __restrict__ dout, float* __restrict__ ws) {
    bool isbf = ws[WS_FLAG] != 0.0f;
    int tid = threadIdx.x;
    int wid = tid >> 6, lane = tid & 63;
    __shared__ __align__(16) float lm[HDIM];
    for (int i = tid * 4; i < HDIM; i += 1024)
        *(float4*)(lm + i) = *(const float4*)(ws + WS_OG + i);
    __syncthreads();
    int r0 = blockIdx.x * 8 + wid * 2;
    float acc0, acc1;
    if (isbf) {
        const bfraw* w0 = (const bfraw*)Wo + (long long)r0 * HDIM;
        uint4 A[8], B[8];
        issue8(w0, lane, A);
        issue8(w0 + HDIM, lane, B);
        __builtin_amdgcn_sched_barrier(0);
        acc0 = consume8(A, lm, lane);
        acc1 = consume8(B, lm, lane);
    } else {
        const float* w0 = (const float*)Wo + (long long)r0 * HDIM;
        acc0 = dot_row_f32(w0, lm, lane);
        acc1 = dot_row_f32(w0 + HDIM, lm, lane);
    }
    acc0 = waveReduce(acc0); acc1 = waveReduce(acc1);
    if (lane == 0) {
        stout(dout, r0,     ldin(x, r0, isbf)     + acc0, isbf);
        stout(dout, r0 + 1, ldin(x, r0 + 1, isbf) + acc1, isbf);
    }
}

extern "C" void kernel_launch(void* const* d_in, const int* in_sizes, int n_in,
                              void* d_out, int out_size, void* d_ws, size_t ws_size,
                              hipStream_t stream) {
    const void* x      = d_in[0];
    const void* st1    = d_in[1];
    const void* st2    = d_in[2];
    const void* ln1w   = d_in[3];
    const void* ln1b   = d_in[4];
    const void* tmx    = d_in[5];
    const void* tmaa   = d_in[6];
    const void* maw1   = d_in[7];
    const void* maw2   = d_in[8];
    const void* tdec   = d_in[9];
    const void* tfirst = d_in[10];
    const void* dw1    = d_in[11];
    const void* dw2    = d_in[12];
    const void* Wr     = d_in[13];
    const void* Wk     = d_in[14];
    const void* Wv     = d_in[15];
    const void* Wg     = d_in[16];
    const void* Wo     = d_in[17];
    const void* lnxw   = d_in[18];
    const void* lnxb   = d_in[19];

    float* ws = (float*)d_ws;

    kS_fused<<<80, 256, 0, stream>>>(x, st1, ln1w, ln1b, tmx, tmaa,
                                     maw1, maw2, d_out, ws);
    kC_big<<<KC_BLOCKS, 256, 0, stream>>>(dw1, dw2, tdec,
                                          Wr, Wk, Wv, Wg, ws);
    kD_heads<<<64, 64, 0, stream>>>(st2, tfirst, lnxw, lnxb, d_out, ws);
    kE_out<<<512, 256, 0, stream>>>(Wo, x, d_out, ws);
}